// Round 6
// baseline (104.847 us; speedup 1.0000x reference)
//
#include <hip/hip_runtime.h>
#include <stdint.h>

#define N_GAUSS 1024
#define H_DIM 768
#define W_DIM 768
#define WL_STRIDE 1040  // fp16 W row stride: row bank offset 8 -> 2-way (free)

typedef _Float16 half8  __attribute__((ext_vector_type(8)));
typedef __fp16   fp16x2 __attribute__((ext_vector_type(2)));
typedef float    f32x4  __attribute__((ext_vector_type(4)));
typedef float    v2f    __attribute__((ext_vector_type(2)));
typedef uint32_t u32x4  __attribute__((ext_vector_type(4)));

// v(y) = exp2(q(y)), q = D*y^2 + c1*y + c0 (-0.5*log2e folded in; q <= 0).
// Second-order multiplicative recurrence along the row (step Delta = 16 px):
//   v_{r+1} = v_r * rho_r,  rho_{r+1} = rho_r * sigma
//   rho_0 = exp2(Delta*(D*(2y0+Delta)+c1)),  sigma = exp2(2*D*Delta^2)
// Chains in fp32 (fp16 chains drift: absmax FAIL); fp16 only at the
// per-step cvt_pkrtz (absmax 0.5 PASS).
//
// R22 = R20 VERBATIM (session best: 58.2 us dispatch, 104.4 headline).
// Reproduction run before declaring the floor.
//
// Final machine model (fits R16/R19/R20/R21 counters):
//  - SIMD issue port is ~saturated at 4 waves/SIMD: VALU ~70% + MFMA
//    ~13% + trans + DS + SALU ~= 95%. VALUBusy ~70% is the steady-state
//    ceiling of this loop REGARDLESS of round packing (R19: perfect
//    4+4+4 rounds -> still 68%; R21: tail-free 3 waves/SIMD -> 59%,
//    WORSE - 3 waves can't feed the port).
//  - Chain cost: 8 v_pk_mul_f32 + 4 cvt_pkrtz per r covering 512
//    gaussian-px. Counters only reconcile if packed-f32 is half-rate
//    (4cyc wave64) -> chain is within ~1.5x of the device's raw f32
//    multiply throughput floor. Per-gp VALU is M*K-invariant across
//    MFMA shapes (32x32x16 gives no reduction); N-waste (3/16 channels)
//    is unreclaimable (exp(quadratic) doesn't factor into B).
//
// Probed and rejected (do not retry):
//   R11 SW-pipelined LDS prefetch: +11 us (compiler already optimal)
//   R13 fp16 chains (16-step): absmax 3.0 FAIL
//   R14 inline-asm v_pk_mul_f32: neutral (packed f32 is half-rate)
//   R15 launch_bounds(256,6) w/ acc[16]: forced spill -> 200 us
//   R17/R18 persistent-row seg loop: ~70 MB scratch daemon, 112-121 us
//   R19 192-px retile, 3072 blk (perfect rounds): 69.5 us - tail theory
//       false from above; anchor duplication is pure cost
//   R21 one-block-per-row, wave-per-seg (3 waves/SIMD, no reduction):
//       60.6 us - 3 waves/SIMD underfeeds the issue port (VALUBusy 59)
//   R20 parallel coalesced epilogue: WIN 64.5 -> 58.2 (this kernel)
//
// Geometry: block = 256 thr = 4 waves over one 256-px col-group; wave =
// 256-gaussian quarter (8 k-tiles) x 16 m-tiles (256 px). 2304 blocks.
// MFMA 16x16x32 f16: A[m=lane&15][k=quad*8+j]; C/D col=lane&15 (ch),
// row=quad*4+reg (px). Coeff LDS: float4 {D,c1,c0,sigma} per gaussian,
// [kt][quad][slot0..8] 9-slot pad -> quad bank starts {0,4,8,12}:
// conflict-free b128. W rows {r,g,b,0} stride 1040 fp16 (2-way = free).
__global__ __launch_bounds__(256, 3) void render_kernel(
    const float2* __restrict__ means2,   // (N,2,1) -> {mx,my}
    const float4* __restrict__ covs4,    // (N,2,2) -> {a,b,c,d}
    const float4* __restrict__ colors4,  // (N,4)   -> {cr,cg,cb,alpha}
    float* __restrict__ out) {
  __shared__ __align__(16) float4 ccf4[32 * 4 * 9];     // 18,432 B (+ red buf)
  __shared__ __align__(16) _Float16 wl[4 * WL_STRIDE];  // 8,320 B

  const int t   = threadIdx.x;          // 0..255
  const int h   = blockIdx.x / 3;       // image row
  const int seg = blockIdx.x % 3;       // 256-px col-group
  const float scale = 1.0f / 767.0f;
  const float x = (float)h * scale;
  const float L = -0.72134752044448170368f;  // -0.5 * log2(e)
  const float Delta = 16.0f * scale;

  // ---- Block prep: 4 gaussians per thread ----
#pragma unroll
  for (int i = 0; i < 4; ++i) {
    const int g = i * 256 + t;
    const float2 mn = means2[g];
    const float4 cv = covs4[g];    // a,b,c,d
    const float4 co = colors4[g];  // cr,cg,cb,alpha
    const float inv = 1.0f / (cv.x * cv.w - cv.y * cv.z);
    const float A  = L * cv.w * inv;
    const float Bc = -L * (cv.y + cv.z) * inv;
    const float D  = L * cv.x * inv;
    const float dx = x - mn.x;
    const float qa = A * dx * dx;
    const float qb = Bc * dx;
    const float c1 = fmaf(-2.0f * D, mn.y, qb);
    const float c0 = fmaf(fmaf(D, mn.y, -qb), mn.y, qa);
    const float sg = __builtin_amdgcn_exp2f(2.0f * D * Delta * Delta);
    ccf4[(g >> 5) * 36 + ((g >> 3) & 3) * 9 + (g & 7)] =
        make_float4(D, c1, c0, sg);
    const float al = co.w;
    wl[0 * WL_STRIDE + g] = (_Float16)(al / (1.0f + expf(-co.x)));
    wl[1 * WL_STRIDE + g] = (_Float16)(al / (1.0f + expf(-co.y)));
    wl[2 * WL_STRIDE + g] = (_Float16)(al / (1.0f + expf(-co.z)));
    wl[3 * WL_STRIDE + g] = (_Float16)0.0f;
  }
  __syncthreads();

  // ---- Per-wave setup: wave = gaussian quarter, 16 m-tiles (256 px) ----
  const int lane = t & 63;
  const int wq   = t >> 6;              // gaussian quarter 0..3
  const int m    = lane & 15;
  const int quad = lane >> 4;
  const int px0  = seg * 256;
  const float y0 = (float)(px0 + m) * scale;
  const float u  = fmaf(2.0f, y0, Delta);   // rho_0 exponent helper
  const int n4 = (m < 3) ? m : 3;

  // wave wq handles global k-tiles wq*8 .. wq*8+7
  const float4* cbase = ccf4 + (wq * 8) * 36 + quad * 9;   // + ktl*36
  const _Float16* wbase = &wl[n4 * WL_STRIDE + (wq * 8) * 32 + quad * 8];

  f32x4 acc[16];
#pragma unroll
  for (int r = 0; r < 16; ++r) acc[r] = (f32x4){0.f, 0.f, 0.f, 0.f};

  for (int ktl = 0; ktl < 8; ++ktl) {
    const float4* cp = cbase + ktl * 36;
    float4 c[8];
#pragma unroll
    for (int j = 0; j < 8; ++j) c[j] = cp[j];   // 8x ds_read_b128, bank-clean

    const half8 b = *(const half8*)(wbase + ktl * 32);

    // anchors + ratios (2 exps per gaussian, bounded fp32)
    v2f vv[4], rr[4], ss[4];
#pragma unroll
    for (int j = 0; j < 8; ++j) {
      const float q0  = fmaf(fmaf(c[j].x, y0, c[j].y), y0, c[j].z);
      const float rex = Delta * fmaf(c[j].x, u, c[j].y);
      vv[j >> 1][j & 1] = __builtin_amdgcn_exp2f(q0);
      rr[j >> 1][j & 1] = __builtin_amdgcn_exp2f(rex);
      ss[j >> 1][j & 1] = c[j].w;
    }

#pragma unroll
    for (int r = 0; r < 16; ++r) {
      u32x4 pa;
#pragma unroll
      for (int p = 0; p < 4; ++p) {
        const fp16x2 hp = __builtin_amdgcn_cvt_pkrtz(vv[p].x, vv[p].y);
        pa[p] = __builtin_bit_cast(uint32_t, hp);
      }
      acc[r] = __builtin_amdgcn_mfma_f32_16x16x32_f16(
          __builtin_bit_cast(half8, pa), b, acc[r], 0, 0, 0);
      if (r < 15) {
#pragma unroll
        for (int p = 0; p < 4; ++p) {   // v_pk_mul_f32 chains
          vv[p] *= rr[p];
          rr[p] *= ss[p];
        }
      }
    }
  }

  // ---- Epilogue: ALL 4 waves write partials, ALL 4 waves sum+store ----
  __syncthreads();                       // all waves done reading ccf4/wl
  float* red = (float*)ccf4;             // 4 sets x 768 floats = 12,288 B
  if (m < 3) {
    float* buf = red + wq * 768;
#pragma unroll
    for (int r = 0; r < 16; ++r) {
#pragma unroll
      for (int reg = 0; reg < 4; ++reg) {
        const int pxl = 16 * r + quad * 4 + reg;   // 0..255
        buf[pxl * 3 + m] = acc[r][reg];            // banks distinct mod 32
      }
    }
  }
  __syncthreads();
  // Block output span is contiguous: out[(h*768+px0)*3 .. +768). Each wave
  // sums a disjoint 192-float slice across the 4 sets, 64 lanes coalesced.
  {
    float* obase = out + ((size_t)h * W_DIM + px0) * 3;
    const int base = wq * 192;
#pragma unroll
    for (int i = 0; i < 3; ++i) {
      const int f = base + i * 64 + lane;
      const float s = red[f] + red[768 + f] + red[1536 + f] + red[2304 + f];
      obase[f] = s;
    }
  }
}

extern "C" void kernel_launch(void* const* d_in, const int* in_sizes, int n_in,
                              void* d_out, int out_size, void* d_ws, size_t ws_size,
                              hipStream_t stream) {
  const float2* means2  = (const float2*)d_in[0];   // (N,2,1)
  const float4* covs4   = (const float4*)d_in[1];   // (N,2,2)
  const float4* colors4 = (const float4*)d_in[2];   // (N,4)
  float* out = (float*)d_out;                       // (768,768,3) fp32

  // 2304 blocks = 768 rows x 3 col-groups; 256 thr = 4 gaussian-quarter waves.
  render_kernel<<<dim3(H_DIM * 3), dim3(256), 0, stream>>>(
      means2, covs4, colors4, out);
}

// Round 7
// 104.692 us; speedup vs baseline: 1.0015x; 1.0015x over previous
//
#include <hip/hip_runtime.h>
#include <stdint.h>

#define N_GAUSS 1024
#define H_DIM 768
#define W_DIM 768
#define WL_STRIDE 1040  // fp16 W row stride: row bank offset 8 -> 2-way (free)

typedef _Float16 half8  __attribute__((ext_vector_type(8)));
typedef __fp16   fp16x2 __attribute__((ext_vector_type(2)));
typedef float    f32x4  __attribute__((ext_vector_type(4)));
typedef float    v2f    __attribute__((ext_vector_type(2)));
typedef uint32_t u32x4  __attribute__((ext_vector_type(4)));

// v(y) = exp2(q(y)), q = D*y^2 + c1*y + c0 (-0.5*log2e folded in; q <= 0).
//
// R23: two-level chain. f32 second-order recurrence at MACRO stride 4:
//   VV_{s+1} = VV_s * PP_s    (VV = v at px offset 4s)
//   PP_{s+1} = PP_s * sigma^16,  PP_0 = rho_0^4 sigma^6 = exp2(4*rex+12*D*Dl^2)
//   RR_{s+1} = RR_s * sigma^4    (RR = rho at macro start, seeds fp16 ratio)
// plus fp16 SUB-chains for the 3 intra-macro steps:
//   va *= rq (v_pk_mul_f16, full-rate), rq *= sigma_h
// va IS the MFMA A operand -> per-step cvt_pkrtz eliminated except at
// macro starts. Chain cost/ktile: 128 pk_f32(4cy)+64 cvt -> 40 pk_f32 +
// 32 cvt + 80 pk_f16(2cy): ~640 -> ~410 cyc (-17% kernel).
// Drift: fp16 error is quadratic in steps ((r^2/2)*2^-11). R13 (15 steps)
// = 3e-2 -> absmax 3.0 FAIL. Here max 3 steps from an f32 anchor with
// fresh f32-seeded rq each macro: 2e-3, ~15-25x less -> predicted absmax
// 0.55-0.75. DECLARED GAMBLE: if FAIL, revert to R22 + declare floor.
// (R13 also proves no fp16-overflow/NaN blowup on this fixed dataset.)
//
// Register discipline: steady live set VV/RR/PP/S4(32) + b/sv/va/rq(16)
// + addr ~= 52-56 VGPR + 64 AGPR acc. __launch_bounds__(256,4) PINS the
// 128-reg budget (4 waves/SIMD): R21 showed 3 waves/SIMD underfeeds the
// port (-15%); a silent 130-reg allocation would do exactly that.
//
// Probed and rejected (do not retry):
//   R11 SW-pipelined LDS prefetch: +11 us; R14 asm pk_mul: neutral
//   R13 FULL fp16 chains: absmax 3.0 FAIL (quadratic drift, 15 steps)
//   R15 launch_bounds(256,6) w/ acc[16]: forced spill -> 200 us
//   R17/R18 persistent-row seg loop: ~70 MB scratch daemon, 112-121 us
//   R19 3072-blk retile (perfect rounds): 69.5 us (duplication > packing)
//   R21 row-block wave-per-seg (3 w/SIMD): 60.6 us (port underfed)
//   R20/R22 parallel epilogue: 58.2-59.1 us (anchor; revert target)
//
// Geometry (R20): block = 256 thr = 4 waves over one 256-px col-group;
// wave = 256-gaussian quarter (8 k-tiles) x 16 m-tiles. 2304 blocks.
// MFMA 16x16x32 f16: A[m=lane&15][k=quad*8+j]; C/D col=lane&15 (ch),
// row=quad*4+reg (px). Coeff LDS float4 {D,c1,c0,sigma^4}, 9-slot pad,
// conflict-free b128. W rows {r,g,b,0} stride 1040 fp16. sigma_h fp16
// table sh16[1024] (2 KB), half8-loadable per (ktile,quad).
__global__ __launch_bounds__(256, 4) void render_kernel(
    const float2* __restrict__ means2,   // (N,2,1) -> {mx,my}
    const float4* __restrict__ covs4,    // (N,2,2) -> {a,b,c,d}
    const float4* __restrict__ colors4,  // (N,4)   -> {cr,cg,cb,alpha}
    float* __restrict__ out) {
  __shared__ __align__(16) float4 ccf4[32 * 4 * 9];     // 18,432 B (+ red buf)
  __shared__ __align__(16) _Float16 wl[4 * WL_STRIDE];  // 8,320 B
  __shared__ __align__(16) _Float16 sh16[N_GAUSS];      // 2,048 B sigma fp16

  const int t   = threadIdx.x;          // 0..255
  const int h   = blockIdx.x / 3;       // image row
  const int seg = blockIdx.x % 3;       // 256-px col-group
  const float scale = 1.0f / 767.0f;
  const float x = (float)h * scale;
  const float L = -0.72134752044448170368f;  // -0.5 * log2(e)
  const float Delta = 16.0f * scale;

  // ---- Block prep: 4 gaussians per thread ----
#pragma unroll
  for (int i = 0; i < 4; ++i) {
    const int g = i * 256 + t;
    const float2 mn = means2[g];
    const float4 cv = covs4[g];    // a,b,c,d
    const float4 co = colors4[g];  // cr,cg,cb,alpha
    const float inv = 1.0f / (cv.x * cv.w - cv.y * cv.z);
    const float A  = L * cv.w * inv;
    const float Bc = -L * (cv.y + cv.z) * inv;
    const float D  = L * cv.x * inv;
    const float dx = x - mn.x;
    const float qa = A * dx * dx;
    const float qb = Bc * dx;
    const float c1 = fmaf(-2.0f * D, mn.y, qb);
    const float c0 = fmaf(fmaf(D, mn.y, -qb), mn.y, qa);
    const float sg1 = __builtin_amdgcn_exp2f(2.0f * D * Delta * Delta);
    const float sg2 = sg1 * sg1;
    const float sg4 = sg2 * sg2;       // sigma^4 for the f32 macro chains
    ccf4[(g >> 5) * 36 + ((g >> 3) & 3) * 9 + (g & 7)] =
        make_float4(D, c1, c0, sg4);
    sh16[g] = (_Float16)sg1;           // sigma for the fp16 sub-chains
    const float al = co.w;
    wl[0 * WL_STRIDE + g] = (_Float16)(al / (1.0f + expf(-co.x)));
    wl[1 * WL_STRIDE + g] = (_Float16)(al / (1.0f + expf(-co.y)));
    wl[2 * WL_STRIDE + g] = (_Float16)(al / (1.0f + expf(-co.z)));
    wl[3 * WL_STRIDE + g] = (_Float16)0.0f;
  }
  __syncthreads();

  // ---- Per-wave setup: wave = gaussian quarter, 16 m-tiles (256 px) ----
  const int lane = t & 63;
  const int wq   = t >> 6;              // gaussian quarter 0..3
  const int m    = lane & 15;
  const int quad = lane >> 4;
  const int px0  = seg * 256;
  const float y0 = (float)(px0 + m) * scale;
  const float u  = fmaf(2.0f, y0, Delta);   // rho_0 exponent helper
  const float K12 = 12.0f * Delta * Delta;  // PP_0 exponent: 4*rex + D*K12
  const int n4 = (m < 3) ? m : 3;

  // wave wq handles global k-tiles wq*8 .. wq*8+7
  const float4* cbase = ccf4 + (wq * 8) * 36 + quad * 9;       // + ktl*36
  const _Float16* wbase = &wl[n4 * WL_STRIDE + (wq * 8) * 32 + quad * 8];
  const _Float16* svbase = &sh16[(wq * 8) * 32 + quad * 8];    // + ktl*32

  f32x4 acc[16];
#pragma unroll
  for (int r = 0; r < 16; ++r) acc[r] = (f32x4){0.f, 0.f, 0.f, 0.f};

  for (int ktl = 0; ktl < 8; ++ktl) {
    const float4* cp = cbase + ktl * 36;

    // anchors: 3 exp2 per gaussian (v, rho, 4-step product), coeffs
    // consumed immediately (register-light, R18-verified pattern)
    v2f VV[4], RR[4], PP[4], S4[4];
#pragma unroll
    for (int j = 0; j < 8; ++j) {
      const float4 cj = cp[j];                       // ds_read_b128
      const float q0  = fmaf(fmaf(cj.x, y0, cj.y), y0, cj.z);
      const float rex = Delta * fmaf(cj.x, u, cj.y);
      const float pe  = fmaf(cj.x, K12, 4.0f * rex); // log2(rho^4 sigma^6)
      VV[j >> 1][j & 1] = __builtin_amdgcn_exp2f(q0);
      RR[j >> 1][j & 1] = __builtin_amdgcn_exp2f(rex);
      PP[j >> 1][j & 1] = __builtin_amdgcn_exp2f(pe);
      S4[j >> 1][j & 1] = cj.w;                      // sigma^4
    }

    const half8 b  = *(const half8*)(wbase + ktl * 32);
    const half8 sv = *(const half8*)(svbase + ktl * 32);  // sigma fp16

    // 4 macros x 4 px: f32 anchors at macro starts, fp16 sub-chains inside
#pragma unroll
    for (int s = 0; s < 4; ++s) {
      u32x4 pav, rqv;
#pragma unroll
      for (int p = 0; p < 4; ++p) {
        pav[p] = __builtin_bit_cast(
            uint32_t, __builtin_amdgcn_cvt_pkrtz(VV[p].x, VV[p].y));
        rqv[p] = __builtin_bit_cast(
            uint32_t, __builtin_amdgcn_cvt_pkrtz(RR[p].x, RR[p].y));
      }
      half8 va = __builtin_bit_cast(half8, pav);
      half8 rq = __builtin_bit_cast(half8, rqv);
      acc[4 * s] = __builtin_amdgcn_mfma_f32_16x16x32_f16(
          va, b, acc[4 * s], 0, 0, 0);
#pragma unroll
      for (int i = 1; i < 4; ++i) {
        va = va * rq;                     // v_pk_mul_f16 x4 (full-rate)
        acc[4 * s + i] = __builtin_amdgcn_mfma_f32_16x16x32_f16(
            va, b, acc[4 * s + i], 0, 0, 0);
        if (i < 3) rq = rq * sv;          // rho advances by sigma
      }
      if (s < 3) {
#pragma unroll
        for (int p = 0; p < 4; ++p) {     // f32 macro transition
          VV[p] *= PP[p];                 // v at next macro start
          RR[p] *= S4[p];                 // rho at next macro start
        }
        if (s < 2) {
#pragma unroll
          for (int p = 0; p < 4; ++p) {   // PP *= sigma^16 (= sigma^8 twice)
            const v2f t8 = S4[p] * S4[p];
            PP[p] *= t8;
            PP[p] *= t8;
          }
        }
      }
    }
  }

  // ---- Epilogue: ALL 4 waves write partials, ALL 4 waves sum+store ----
  __syncthreads();                       // all waves done reading ccf4/wl
  float* red = (float*)ccf4;             // 4 sets x 768 floats = 12,288 B
  if (m < 3) {
    float* buf = red + wq * 768;
#pragma unroll
    for (int r = 0; r < 16; ++r) {
#pragma unroll
      for (int reg = 0; reg < 4; ++reg) {
        const int pxl = 16 * r + quad * 4 + reg;   // 0..255
        buf[pxl * 3 + m] = acc[r][reg];            // banks distinct mod 32
      }
    }
  }
  __syncthreads();
  // Block output span is contiguous: out[(h*768+px0)*3 .. +768). Each wave
  // sums a disjoint 192-float slice across the 4 sets, 64 lanes coalesced.
  {
    float* obase = out + ((size_t)h * W_DIM + px0) * 3;
    const int base = wq * 192;
#pragma unroll
    for (int i = 0; i < 3; ++i) {
      const int f = base + i * 64 + lane;
      const float s = red[f] + red[768 + f] + red[1536 + f] + red[2304 + f];
      obase[f] = s;
    }
  }
}

extern "C" void kernel_launch(void* const* d_in, const int* in_sizes, int n_in,
                              void* d_out, int out_size, void* d_ws, size_t ws_size,
                              hipStream_t stream) {
  const float2* means2  = (const float2*)d_in[0];   // (N,2,1)
  const float4* covs4   = (const float4*)d_in[1];   // (N,2,2)
  const float4* colors4 = (const float4*)d_in[2];   // (N,4)
  float* out = (float*)d_out;                       // (768,768,3) fp32

  // 2304 blocks = 768 rows x 3 col-groups; 256 thr = 4 gaussian-quarter waves.
  render_kernel<<<dim3(H_DIM * 3), dim3(256), 0, stream>>>(
      means2, covs4, colors4, out);
}

// Round 8
// 103.119 us; speedup vs baseline: 1.0168x; 1.0153x over previous
//
#include <hip/hip_runtime.h>
#include <stdint.h>

#define N_GAUSS 1024
#define H_DIM 768
#define W_DIM 768
#define WL_STRIDE 1040  // fp16 W row stride: row bank offset 8 -> 2-way (free)

typedef _Float16 half8  __attribute__((ext_vector_type(8)));
typedef __fp16   fp16x2 __attribute__((ext_vector_type(2)));
typedef float    f32x4  __attribute__((ext_vector_type(4)));
typedef float    v2f    __attribute__((ext_vector_type(2)));
typedef uint32_t u32x4  __attribute__((ext_vector_type(4)));

// v(y) = exp2(q(y)), q = D*y^2 + c1*y + c0 (-0.5*log2e folded in; q <= 0).
//
// R24 = R23 + fast prep transcendentals. Without -ffast-math each
// 1.0f/x is the ~10-inst div_scale/div_fmas/div_fixup sequence and each
// expf carries range-fixup code; per thread that's ~180 extra inst
// (4 dets + 12 sigmoids), duplicated in all 2304 blocks ~= 1.5 us.
// v_rcp_f32 (~2^-22 rel err) + direct exp2(x*log2e) are 500x below the
// fp16 A-operand quantization (2^-11) that dominates the error budget.
// PRE-COMMITMENT: if this lands flat (>=56.5 us), declare ROOFLINE.
//
// R23 (current anchor, 56.7 us): two-level chain. f32 macro recurrence
// stride 4 (VV*=PP, PP*=sigma^16, RR*=sigma^4; PP_0=exp2(4rex+12D*Dl^2))
// + fp16 sub-chains (va*=rq, rq*=sigma_h) for the 3 intra-macro steps;
// va IS the MFMA A operand (per-step cvt eliminated). absmax PASS.
//
// NOTE: "absmax: 0.5" in results is the PASS TOLERANCE, not a measured
// value (bit-identical across R16/R22/R23). R13's 3.0 was a measured
// FAIL. Scaling R13's quadratic fp16 drift (15 steps -> 3.0) to a
// stride-8 macro (7 steps) predicts ~0.66 > 0.5 -> macro-8 is a
// predicted FAIL, not a gamble. Do not attempt.
//
// Probed and rejected (do not retry):
//   R11 SW-pipelined LDS prefetch: +11 us; R14 asm pk_mul: neutral
//   R13 FULL fp16 chains: absmax 3.0 FAIL (quadratic drift, 15 steps)
//   R15 launch_bounds(256,6) w/ acc[16]: forced spill -> 200 us
//   R17/R18 persistent-row seg loop: ~70 MB scratch daemon, 112-121 us
//   R19 3072-blk retile (perfect rounds): 69.5 us (duplication > packing)
//   R21 row-block wave-per-seg (3 w/SIMD): 60.6 us (port underfed)
//   R20/R22 parallel epilogue: 58.2-59.1 us; R23 two-level chain: 56.7
//   (Residual ~4 MB scratch from anchor-phase peak ~68>64 VGPR: once-
//    per-thread, latency-hidden; fixing it re-adds exp2s or drift.)
//
// Geometry (R20): block = 256 thr = 4 waves over one 256-px col-group;
// wave = 256-gaussian quarter (8 k-tiles) x 16 m-tiles. 2304 blocks.
// MFMA 16x16x32 f16: A[m=lane&15][k=quad*8+j]; C/D col=lane&15 (ch),
// row=quad*4+reg (px). Coeff LDS float4 {D,c1,c0,sigma^4}, 9-slot pad,
// conflict-free b128. W rows {r,g,b,0} stride 1040 fp16. sigma_h fp16
// table sh16[1024] (2 KB), half8-loadable per (ktile,quad).
__global__ __launch_bounds__(256, 4) void render_kernel(
    const float2* __restrict__ means2,   // (N,2,1) -> {mx,my}
    const float4* __restrict__ covs4,    // (N,2,2) -> {a,b,c,d}
    const float4* __restrict__ colors4,  // (N,4)   -> {cr,cg,cb,alpha}
    float* __restrict__ out) {
  __shared__ __align__(16) float4 ccf4[32 * 4 * 9];     // 18,432 B (+ red buf)
  __shared__ __align__(16) _Float16 wl[4 * WL_STRIDE];  // 8,320 B
  __shared__ __align__(16) _Float16 sh16[N_GAUSS];      // 2,048 B sigma fp16

  const int t   = threadIdx.x;          // 0..255
  const int h   = blockIdx.x / 3;       // image row
  const int seg = blockIdx.x % 3;       // 256-px col-group
  const float scale = 1.0f / 767.0f;
  const float x = (float)h * scale;
  const float L = -0.72134752044448170368f;  // -0.5 * log2(e)
  const float LOG2E = 1.44269504088896340736f;
  const float Delta = 16.0f * scale;

  // ---- Block prep: 4 gaussians per thread (rcp/exp2 fast path) ----
#pragma unroll
  for (int i = 0; i < 4; ++i) {
    const int g = i * 256 + t;
    const float2 mn = means2[g];
    const float4 cv = covs4[g];    // a,b,c,d
    const float4 co = colors4[g];  // cr,cg,cb,alpha
    const float inv = __builtin_amdgcn_rcpf(cv.x * cv.w - cv.y * cv.z);
    const float A  = L * cv.w * inv;
    const float Bc = -L * (cv.y + cv.z) * inv;
    const float D  = L * cv.x * inv;
    const float dx = x - mn.x;
    const float qa = A * dx * dx;
    const float qb = Bc * dx;
    const float c1 = fmaf(-2.0f * D, mn.y, qb);
    const float c0 = fmaf(fmaf(D, mn.y, -qb), mn.y, qa);
    const float sg1 = __builtin_amdgcn_exp2f(2.0f * D * Delta * Delta);
    const float sg2 = sg1 * sg1;
    const float sg4 = sg2 * sg2;       // sigma^4 for the f32 macro chains
    ccf4[(g >> 5) * 36 + ((g >> 3) & 3) * 9 + (g & 7)] =
        make_float4(D, c1, c0, sg4);
    sh16[g] = (_Float16)sg1;           // sigma for the fp16 sub-chains
    const float al = co.w;
    // sigmoid(x) = rcp(1 + exp2(-x*log2e)); rcp err 2^-22 << fp16 2^-11
    wl[0 * WL_STRIDE + g] = (_Float16)(al * __builtin_amdgcn_rcpf(
        1.0f + __builtin_amdgcn_exp2f(-co.x * LOG2E)));
    wl[1 * WL_STRIDE + g] = (_Float16)(al * __builtin_amdgcn_rcpf(
        1.0f + __builtin_amdgcn_exp2f(-co.y * LOG2E)));
    wl[2 * WL_STRIDE + g] = (_Float16)(al * __builtin_amdgcn_rcpf(
        1.0f + __builtin_amdgcn_exp2f(-co.z * LOG2E)));
    wl[3 * WL_STRIDE + g] = (_Float16)0.0f;
  }
  __syncthreads();

  // ---- Per-wave setup: wave = gaussian quarter, 16 m-tiles (256 px) ----
  const int lane = t & 63;
  const int wq   = t >> 6;              // gaussian quarter 0..3
  const int m    = lane & 15;
  const int quad = lane >> 4;
  const int px0  = seg * 256;
  const float y0 = (float)(px0 + m) * scale;
  const float u  = fmaf(2.0f, y0, Delta);   // rho_0 exponent helper
  const float K12 = 12.0f * Delta * Delta;  // PP_0 exponent: 4*rex + D*K12
  const int n4 = (m < 3) ? m : 3;

  // wave wq handles global k-tiles wq*8 .. wq*8+7
  const float4* cbase = ccf4 + (wq * 8) * 36 + quad * 9;       // + ktl*36
  const _Float16* wbase = &wl[n4 * WL_STRIDE + (wq * 8) * 32 + quad * 8];
  const _Float16* svbase = &sh16[(wq * 8) * 32 + quad * 8];    // + ktl*32

  f32x4 acc[16];
#pragma unroll
  for (int r = 0; r < 16; ++r) acc[r] = (f32x4){0.f, 0.f, 0.f, 0.f};

  for (int ktl = 0; ktl < 8; ++ktl) {
    const float4* cp = cbase + ktl * 36;

    // anchors: 3 exp2 per gaussian (v, rho, 4-step product), coeffs
    // consumed immediately (register-light, R18-verified pattern)
    v2f VV[4], RR[4], PP[4], S4[4];
#pragma unroll
    for (int j = 0; j < 8; ++j) {
      const float4 cj = cp[j];                       // ds_read_b128
      const float q0  = fmaf(fmaf(cj.x, y0, cj.y), y0, cj.z);
      const float rex = Delta * fmaf(cj.x, u, cj.y);
      const float pe  = fmaf(cj.x, K12, 4.0f * rex); // log2(rho^4 sigma^6)
      VV[j >> 1][j & 1] = __builtin_amdgcn_exp2f(q0);
      RR[j >> 1][j & 1] = __builtin_amdgcn_exp2f(rex);
      PP[j >> 1][j & 1] = __builtin_amdgcn_exp2f(pe);
      S4[j >> 1][j & 1] = cj.w;                      // sigma^4
    }

    const half8 b  = *(const half8*)(wbase + ktl * 32);
    const half8 sv = *(const half8*)(svbase + ktl * 32);  // sigma fp16

    // 4 macros x 4 px: f32 anchors at macro starts, fp16 sub-chains inside
#pragma unroll
    for (int s = 0; s < 4; ++s) {
      u32x4 pav, rqv;
#pragma unroll
      for (int p = 0; p < 4; ++p) {
        pav[p] = __builtin_bit_cast(
            uint32_t, __builtin_amdgcn_cvt_pkrtz(VV[p].x, VV[p].y));
        rqv[p] = __builtin_bit_cast(
            uint32_t, __builtin_amdgcn_cvt_pkrtz(RR[p].x, RR[p].y));
      }
      half8 va = __builtin_bit_cast(half8, pav);
      half8 rq = __builtin_bit_cast(half8, rqv);
      acc[4 * s] = __builtin_amdgcn_mfma_f32_16x16x32_f16(
          va, b, acc[4 * s], 0, 0, 0);
#pragma unroll
      for (int i = 1; i < 4; ++i) {
        va = va * rq;                     // v_pk_mul_f16 x4 (full-rate)
        acc[4 * s + i] = __builtin_amdgcn_mfma_f32_16x16x32_f16(
            va, b, acc[4 * s + i], 0, 0, 0);
        if (i < 3) rq = rq * sv;          // rho advances by sigma
      }
      if (s < 3) {
#pragma unroll
        for (int p = 0; p < 4; ++p) {     // f32 macro transition
          VV[p] *= PP[p];                 // v at next macro start
          RR[p] *= S4[p];                 // rho at next macro start
        }
        if (s < 2) {
#pragma unroll
          for (int p = 0; p < 4; ++p) {   // PP *= sigma^16 (= sigma^8 twice)
            const v2f t8 = S4[p] * S4[p];
            PP[p] *= t8;
            PP[p] *= t8;
          }
        }
      }
    }
  }

  // ---- Epilogue: ALL 4 waves write partials, ALL 4 waves sum+store ----
  __syncthreads();                       // all waves done reading ccf4/wl
  float* red = (float*)ccf4;             // 4 sets x 768 floats = 12,288 B
  if (m < 3) {
    float* buf = red + wq * 768;
#pragma unroll
    for (int r = 0; r < 16; ++r) {
#pragma unroll
      for (int reg = 0; reg < 4; ++reg) {
        const int pxl = 16 * r + quad * 4 + reg;   // 0..255
        buf[pxl * 3 + m] = acc[r][reg];            // banks distinct mod 32
      }
    }
  }
  __syncthreads();
  // Block output span is contiguous: out[(h*768+px0)*3 .. +768). Each wave
  // sums a disjoint 192-float slice across the 4 sets, 64 lanes coalesced.
  {
    float* obase = out + ((size_t)h * W_DIM + px0) * 3;
    const int base = wq * 192;
#pragma unroll
    for (int i = 0; i < 3; ++i) {
      const int f = base + i * 64 + lane;
      const float s = red[f] + red[768 + f] + red[1536 + f] + red[2304 + f];
      obase[f] = s;
    }
  }
}

extern "C" void kernel_launch(void* const* d_in, const int* in_sizes, int n_in,
                              void* d_out, int out_size, void* d_ws, size_t ws_size,
                              hipStream_t stream) {
  const float2* means2  = (const float2*)d_in[0];   // (N,2,1)
  const float4* covs4   = (const float4*)d_in[1];   // (N,2,2)
  const float4* colors4 = (const float4*)d_in[2];   // (N,4)
  float* out = (float*)d_out;                       // (768,768,3) fp32

  // 2304 blocks = 768 rows x 3 col-groups; 256 thr = 4 gaussian-quarter waves.
  render_kernel<<<dim3(H_DIM * 3), dim3(256), 0, stream>>>(
      means2, covs4, colors4, out);
}